// Round 13
// baseline (229.694 us; speedup 1.0000x reference)
//
#include <hip/hip_runtime.h>
#include <hip/hip_bf16.h>
#include <math.h>

#define D     256
#define D2    512
#define HH    8192
#define NAG   64
#define NROWS 2048
#define KSPL  16    // recall K-split
#define QSPL  32    // query h-split
#define ESPL  32    // exp h-split

typedef short  s16x8 __attribute__((ext_vector_type(8)));
typedef __bf16 b16x8 __attribute__((ext_vector_type(8)));
typedef float  f32x4 __attribute__((ext_vector_type(4)));

template <typename T>
__device__ __forceinline__ auto mfma_try(T a, T b, f32x4 c, int)
    -> decltype(__builtin_amdgcn_mfma_f32_16x16x32_bf16(a, b, c, 0, 0, 0))
{ return __builtin_amdgcn_mfma_f32_16x16x32_bf16(a, b, c, 0, 0, 0); }

template <typename T>
__device__ __forceinline__ f32x4 mfma_try(T a, T b, f32x4 c, long)
{
    return __builtin_amdgcn_mfma_f32_16x16x32_bf16(
        __builtin_bit_cast(b16x8, a), __builtin_bit_cast(b16x8, b), c, 0, 0, 0);
}

__device__ __forceinline__ f32x4 MFMA(s16x8 a, s16x8 b, f32x4 c)
{ return mfma_try(a, b, c, 0); }

__device__ __forceinline__ float gelu_f(float x) {
    return 0.5f * x * (1.0f + erff(x * 0.70710678118654752440f));
}
__device__ __forceinline__ float sigmoid_f(float x) {
    return 1.0f / (1.0f + expf(-x));
}
__device__ __forceinline__ short f2bf(float x) {
    __hip_bfloat16 h(x);
    return __builtin_bit_cast(short, h);
}
__device__ __forceinline__ float bf2f(short s) {
    unsigned u = ((unsigned)(unsigned short)s) << 16;
    return __builtin_bit_cast(float, u);
}

// ------------------------------------------------ transpose f32 -> bf16
__device__ __forceinline__ void transpose_body(
    const float* __restrict__ src, short* __restrict__ dst, int R, int C, int lb)
{
    __shared__ float tl[64][65];
    const int t = threadIdx.x;
    const int Ctiles = C >> 6;
    const int bc = lb % Ctiles, br = lb / Ctiles;
    const int r0 = br * 64, c0 = bc * 64;
    for (int p = 0; p < 16; ++p) {
        int e = p * 256 + t; int i = e >> 6, j = e & 63;
        tl[i][j] = src[(size_t)(r0 + i) * C + c0 + j];
    }
    __syncthreads();
    for (int p = 0; p < 16; ++p) {
        int e = p * 256 + t; int jj = e >> 6, ii = e & 63;
        dst[(size_t)(c0 + jj) * R + r0 + ii] = f2bf(tl[ii][jj]);
    }
}

__global__ __launch_bounds__(256) void k_prep_weights(
    const float* __restrict__ Wh, const float* __restrict__ Wf,
    const float* __restrict__ Wp, const float* __restrict__ Wd1,
    const float* __restrict__ Wd2, const float* __restrict__ Wg,
    const float* __restrict__ Wa,
    short* __restrict__ WhT, short* __restrict__ WfT,
    short* __restrict__ WpT, short* __restrict__ Wd1T,
    short* __restrict__ Wd2T, short* __restrict__ WgT,
    short* __restrict__ WaT)
{
    const int b = blockIdx.x;
    if      (b < 512)  { transpose_body(Wh,  WhT,  256,  HH, b);        }
    else if (b < 1024) { transpose_body(Wf,  WfT,  HH,  256, b - 512);  }
    else if (b < 1056) { transpose_body(Wp,  WpT,  512, 256, b - 1024); }
    else if (b < 1088) { transpose_body(Wd1, Wd1T, 512, 256, b - 1056); }
    else if (b < 1104) { transpose_body(Wd2, Wd2T, 256, 256, b - 1088); }
    else if (b < 1136) { transpose_body(Wg,  WgT,  512, 256, b - 1104); }
    else               { transpose_body(Wa,  WaT,  256, 256, b - 1136); }
}

// ------------------------------------------------ pure streaming: ebf = bf16(ep+cr)
__global__ __launch_bounds__(256) void k_prep_e(
    const float* __restrict__ ep, const float* __restrict__ cr,
    short* __restrict__ ebf)
{
    const size_t i0 = ((size_t)blockIdx.x * 256 + threadIdx.x) * 8;
    const size_t stride = (size_t)gridDim.x * 256 * 8;
    for (size_t i = i0; i < (size_t)NROWS * HH; i += stride) {
        float4 e0 = *(const float4*)(ep + i), e1 = *(const float4*)(ep + i + 4);
        float4 c0 = *(const float4*)(cr + i), c1 = *(const float4*)(cr + i + 4);
        s16x8 ev;
        ev[0] = f2bf(e0.x + c0.x); ev[1] = f2bf(e0.y + c0.y);
        ev[2] = f2bf(e0.z + c0.z); ev[3] = f2bf(e0.w + c0.w);
        ev[4] = f2bf(e1.x + c1.x); ev[5] = f2bf(e1.y + c1.y);
        ev[6] = f2bf(e1.z + c1.z); ev[7] = f2bf(e1.w + c1.w);
        *(s16x8*)(ebf + i) = ev;
    }
}

// ------------------------------------------------ perception mega: LN + Wp GEMM + GELU
__global__ __launch_bounds__(256) void k_perc_mega(
    const float* __restrict__ sig, const float* __restrict__ act,
    const float* __restrict__ pers, const float* __restrict__ chr,
    const float* __restrict__ lng, const float* __restrict__ lnb,
    const short* __restrict__ WpT, const float* __restrict__ bp,
    short* __restrict__ percbf)
{
    __shared__ __align__(16) short xb[16 * 512];
    const int t = threadIdx.x, l = t & 63, w = t >> 6;
    const int l15 = l & 15, lg = l >> 4;
    const int r0 = blockIdx.x * 16;
    const int axor = (l15 & 7) << 4;

    for (int rr = 0; rr < 4; ++rr) {
        const int rloc = w * 4 + rr, row = r0 + rloc;
        const int n = row & (NAG - 1);
        const int c0 = l * 8;
        float v[8];
        if (l < 32) {
            const float* sp = sig  + (size_t)row * D + c0;
            const float* pp = pers + (size_t)n * D + c0;
            const float* cp = chr  + (size_t)n * D + c0;
            float4 s0 = *(const float4*)sp, s1 = *(const float4*)(sp + 4);
            float4 p0 = *(const float4*)pp, p1 = *(const float4*)(pp + 4);
            float4 q0 = *(const float4*)cp, q1 = *(const float4*)(cp + 4);
            v[0] = s0.x * (1.f + 0.1f * (p0.x + 0.3f * q0.x));
            v[1] = s0.y * (1.f + 0.1f * (p0.y + 0.3f * q0.y));
            v[2] = s0.z * (1.f + 0.1f * (p0.z + 0.3f * q0.z));
            v[3] = s0.w * (1.f + 0.1f * (p0.w + 0.3f * q0.w));
            v[4] = s1.x * (1.f + 0.1f * (p1.x + 0.3f * q1.x));
            v[5] = s1.y * (1.f + 0.1f * (p1.y + 0.3f * q1.y));
            v[6] = s1.z * (1.f + 0.1f * (p1.z + 0.3f * q1.z));
            v[7] = s1.w * (1.f + 0.1f * (p1.w + 0.3f * q1.w));
        } else {
            const float* ap = act + (size_t)row * D + (c0 - D);
            float4 a0 = *(const float4*)ap, a1 = *(const float4*)(ap + 4);
            v[0] = a0.x; v[1] = a0.y; v[2] = a0.z; v[3] = a0.w;
            v[4] = a1.x; v[5] = a1.y; v[6] = a1.z; v[7] = a1.w;
        }
        float s = 0.f;
        #pragma unroll
        for (int i = 0; i < 8; ++i) s += v[i];
        #pragma unroll
        for (int m = 1; m < 64; m <<= 1) s += __shfl_xor(s, m);
        const float mu = s * (1.0f / 512.0f);
        float q = 0.f;
        #pragma unroll
        for (int i = 0; i < 8; ++i) { float c = v[i] - mu; q += c * c; }
        #pragma unroll
        for (int m = 1; m < 64; m <<= 1) q += __shfl_xor(q, m);
        const float rstd = rsqrtf(q * (1.0f / 512.0f) + 1e-5f);
        float4 g0 = *(const float4*)(lng + c0), g1 = *(const float4*)(lng + c0 + 4);
        float4 b0 = *(const float4*)(lnb + c0), b1 = *(const float4*)(lnb + c0 + 4);
        const float gg[8] = {g0.x, g0.y, g0.z, g0.w, g1.x, g1.y, g1.z, g1.w};
        const float bb[8] = {b0.x, b0.y, b0.z, b0.w, b1.x, b1.y, b1.z, b1.w};
        s16x8 o;
        #pragma unroll
        for (int i = 0; i < 8; ++i) o[i] = f2bf((v[i] - mu) * rstd * gg[i] + bb[i]);
        *(s16x8*)((char*)xb + rloc * 1024 + ((c0 * 2) ^ ((rloc & 7) << 4))) = o;
    }
    __syncthreads();

    s16x8 afr[16];
    #pragma unroll
    for (int ks = 0; ks < 16; ++ks)
        afr[ks] = *(const s16x8*)((char*)xb + l15 * 1024 + (((ks * 32 + lg * 8) * 2) ^ axor));
    #pragma unroll
    for (int nt = 0; nt < 4; ++nt) {
        const int col = w * 64 + nt * 16 + l15;
        f32x4 acc = {0.f, 0.f, 0.f, 0.f};
        const short* bp_ = WpT + (size_t)col * 512 + lg * 8;
        #pragma unroll
        for (int ks = 0; ks < 16; ++ks)
            acc = MFMA(afr[ks], *(const s16x8*)(bp_ + ks * 32), acc);
        const float bv = bp[col];
        #pragma unroll
        for (int j = 0; j < 4; ++j)
            percbf[(size_t)(r0 + lg * 4 + j) * D + col] = f2bf(gelu_f(acc[j] + bv));
    }
}

// ------------------------------------------------ query (proven structure, QSPL=32)
__global__ __launch_bounds__(256) void k_query(
    const short* __restrict__ percbf, const short* __restrict__ WhT,
    const float* __restrict__ bh, const short* __restrict__ ebf,
    const float* __restrict__ keyf, const float* __restrict__ Wm,
    float* __restrict__ sim_part, float* __restrict__ dot_part)
{
    __shared__ __align__(16) short percs[64 * 256];
    __shared__ __align__(16) short whs[16 * 256];
    __shared__ __align__(16) short es[64 * 20];
    __shared__ __align__(16) short ks2[64 * 20];
    const int t = threadIdx.x;
    const int l = t & 63, w = t >> 6;
    const int l15 = l & 15, lg = l >> 4;
    const int r0 = blockIdx.y * 64;
    const int hb0 = blockIdx.x * (HH / QSPL);
    const int axor = (l15 & 7) << 4;

    for (int p = 0; p < 8; ++p) {
        int e = p * 2048 + t * 8; int r = e >> 8, k = e & 255;
        s16x8 v = *(const s16x8*)(percbf + (size_t)(r0 + r) * 256 + k);
        *(s16x8*)((char*)percs + r * 512 + ((k * 2) ^ ((r & 7) << 4))) = v;
    }
    __syncthreads();

    const int arow = (w * 16 + l15) * 512;
    s16x8 afr[8];
    #pragma unroll
    for (int ks = 0; ks < 8; ++ks)
        afr[ks] = *(const s16x8*)((const char*)percs + arow + ((ks * 64 + lg * 16) ^ axor));

    float psim[4] = {0, 0, 0, 0}, pdot[4] = {0, 0, 0, 0};

    for (int nt = 0; nt < (HH / QSPL) / 16; ++nt) {
        const int hg0 = hb0 + nt * 16;
        for (int p = 0; p < 2; ++p) {
            int e = p * 2048 + t * 8; int hh = e >> 8, k = e & 255;
            s16x8 v = *(const s16x8*)(WhT + (size_t)(hg0 + hh) * 256 + k);
            *(s16x8*)((char*)whs + hh * 512 + ((k * 2) ^ ((hh & 7) << 4))) = v;
        }
        {
            int e = t * 4; int r = e >> 4, hh = e & 15;
            short4 v = *(const short4*)(ebf + (size_t)(r0 + r) * HH + hg0 + hh);
            es[r * 20 + hh + 0] = v.x; es[r * 20 + hh + 1] = v.y;
            es[r * 20 + hh + 2] = v.z; es[r * 20 + hh + 3] = v.w;
            float4 kv = *(const float4*)(keyf + (size_t)r * HH + hg0 + hh);
            ks2[r * 20 + hh + 0] = f2bf(kv.x); ks2[r * 20 + hh + 1] = f2bf(kv.y);
            ks2[r * 20 + hh + 2] = f2bf(kv.z); ks2[r * 20 + hh + 3] = f2bf(kv.w);
        }
        __syncthreads();

        f32x4 acc = {0.f, 0.f, 0.f, 0.f};
        #pragma unroll
        for (int ks = 0; ks < 8; ++ks) {
            s16x8 b = *(const s16x8*)((const char*)whs + l15 * 512 + ((ks * 64 + lg * 16) ^ axor));
            acc = MFMA(afr[ks], b, acc);
        }
        const int h = hg0 + l15;
        const float bhv = bh[h];
        const float wmv = Wm[D + h];
        #pragma unroll
        for (int j = 0; j < 4; ++j) {
            const int rl = w * 16 + lg * 4 + j;
            const float q = tanhf(acc[j] + bhv);
            psim[j] += q * bf2f(es[rl * 20 + l15]) * bf2f(ks2[rl * 20 + l15]);
            pdot[j] += q * wmv;
        }
        __syncthreads();
    }

    #pragma unroll
    for (int j = 0; j < 4; ++j) {
        float s = psim[j], d = pdot[j];
        for (int m = 1; m < 16; m <<= 1) { s += __shfl_xor(s, m); d += __shfl_xor(d, m); }
        if (l15 == 0) {
            const int row = r0 + w * 16 + lg * 4 + j;
            sim_part[blockIdx.x * NROWS + row] = s;
            dot_part[blockIdx.x * NROWS + row] = d;
        }
    }
}

// ------------------------------------------------ recall GEMM (proven, KSPL=16)
__global__ __launch_bounds__(256) void k_recall(
    const short* __restrict__ ebf, const short* __restrict__ WfT,
    float* __restrict__ rpart)
{
    __shared__ __align__(16) short as_[64 * 64];
    __shared__ __align__(16) short bs[256 * 64];
    const int t = threadIdx.x, l = t & 63, w = t >> 6;
    const int l15 = l & 15, lg = l >> 4;
    const int r0 = blockIdx.y * 64;
    const int kc0 = blockIdx.x * (HH / KSPL);
    const int axor = (l15 & 7) << 4;

    f32x4 acc[16];
    #pragma unroll
    for (int i = 0; i < 16; ++i) acc[i] = {0.f, 0.f, 0.f, 0.f};

    for (int kk = 0; kk < HH / KSPL; kk += 64) {
        __syncthreads();
        for (int p = 0; p < 2; ++p) {
            int e = p * 2048 + t * 8; int r = e >> 6, k = e & 63;
            s16x8 v = *(const s16x8*)(ebf + (size_t)(r0 + r) * HH + kc0 + kk + k);
            *(s16x8*)((char*)as_ + r * 128 + ((k * 2) ^ ((r & 7) << 4))) = v;
        }
        for (int p = 0; p < 8; ++p) {
            int e = p * 2048 + t * 8; int n = e >> 6, k = e & 63;
            s16x8 v = *(const s16x8*)(WfT + (size_t)n * HH + kc0 + kk + k);
            *(s16x8*)((char*)bs + n * 128 + ((k * 2) ^ ((n & 7) << 4))) = v;
        }
        __syncthreads();
        const int abase = (w * 16 + l15) * 128;
        s16x8 a0 = *(const s16x8*)((const char*)as_ + abase + ((lg * 16) ^ axor));
        s16x8 a1 = *(const s16x8*)((const char*)as_ + abase + ((64 + lg * 16) ^ axor));
        #pragma unroll
        for (int nt = 0; nt < 16; ++nt) {
            const int bbase = (nt * 16 + l15) * 128;
            s16x8 b0 = *(const s16x8*)((const char*)bs + bbase + ((lg * 16) ^ axor));
            s16x8 b1 = *(const s16x8*)((const char*)bs + bbase + ((64 + lg * 16) ^ axor));
            acc[nt] = MFMA(a0, b0, acc[nt]);
            acc[nt] = MFMA(a1, b1, acc[nt]);
        }
    }
    #pragma unroll
    for (int nt = 0; nt < 16; ++nt) {
        #pragma unroll
        for (int j = 0; j < 4; ++j) {
            const int row = r0 + w * 16 + lg * 4 + j;
            rpart[((size_t)blockIdx.x * NROWS + row) * D + nt * 16 + l15] = acc[nt][j];
        }
    }
}

// ------------------------------------------------ decision mega: LN+W1+GELU+W2+gate+LN+act+mem_gate
__global__ __launch_bounds__(256) void k_dec_mega(
    const short* __restrict__ percbf, const float* __restrict__ rpart,
    const float* __restrict__ bfrom, const float* __restrict__ sim_part,
    const float* __restrict__ lng, const float* __restrict__ lnb,
    const short* __restrict__ Wd1T, const float* __restrict__ bd1,
    const short* __restrict__ Wd2T, const float* __restrict__ bd2,
    const float* __restrict__ pers, const float* __restrict__ prev,
    const short* __restrict__ WgT, const float* __restrict__ bg,
    const float* __restrict__ lnog, const float* __restrict__ lnob,
    const short* __restrict__ WaT, const float* __restrict__ ba,
    const float* __restrict__ Wm, const float* __restrict__ bm,
    const float* __restrict__ dot_part,
    float* __restrict__ out_act, float* __restrict__ out_st,
    short* __restrict__ stbf, float* __restrict__ out_mg)
{
    __shared__ __align__(16) short xb[16 * 512];
    __shared__ __align__(16) short hb[16 * 256];
    __shared__ __align__(16) float xf[16][512];
    __shared__ float red1[4][16], red2[4][16];
    const int t = threadIdx.x, l = t & 63, w = t >> 6;
    const int l15 = l & 15, lg = l >> 4;
    const int r0 = blockIdx.x * 16;
    const int axor = (l15 & 7) << 4;

    // --- Phase 1: dec_in build + LN(512) -> xb
    for (int rr = 0; rr < 4; ++rr) {
        const int rloc = w * 4 + rr, row = r0 + rloc;
        float sr = (l < QSPL) ? sim_part[l * NROWS + row] : 0.f;
        #pragma unroll
        for (int m = 1; m < 32; m <<= 1) sr += __shfl_xor(sr, m);
        sr = __shfl(sr, 0);
        const float strength = sigmoid_f(sr * (1.0f / (float)HH));
        const int c0 = l * 8;
        float v[8];
        if (l < 32) {
            s16x8 pv = *(const s16x8*)(percbf + (size_t)row * D + c0);
            #pragma unroll
            for (int i = 0; i < 8; ++i) v[i] = bf2f(pv[i]);
        } else {
            const int c = c0 - D;
            float a[8] = {0, 0, 0, 0, 0, 0, 0, 0};
            for (int ks = 0; ks < KSPL; ++ks) {
                const float* rp = rpart + ((size_t)ks * NROWS + row) * D + c;
                float4 x0 = *(const float4*)rp, x1 = *(const float4*)(rp + 4);
                a[0] += x0.x; a[1] += x0.y; a[2] += x0.z; a[3] += x0.w;
                a[4] += x1.x; a[5] += x1.y; a[6] += x1.z; a[7] += x1.w;
            }
            float4 f0 = *(const float4*)(bfrom + c), f1 = *(const float4*)(bfrom + c + 4);
            const float fb[8] = {f0.x, f0.y, f0.z, f0.w, f1.x, f1.y, f1.z, f1.w};
            #pragma unroll
            for (int i = 0; i < 8; ++i) v[i] = (a[i] + fb[i]) * strength;
        }
        float s = 0.f;
        #pragma unroll
        for (int i = 0; i < 8; ++i) s += v[i];
        #pragma unroll
        for (int m = 1; m < 64; m <<= 1) s += __shfl_xor(s, m);
        const float mu = s * (1.0f / 512.0f);
        float q = 0.f;
        #pragma unroll
        for (int i = 0; i < 8; ++i) { float c = v[i] - mu; q += c * c; }
        #pragma unroll
        for (int m = 1; m < 64; m <<= 1) q += __shfl_xor(q, m);
        const float rstd = rsqrtf(q * (1.0f / 512.0f) + 1e-5f);
        float4 g0 = *(const float4*)(lng + c0), g1 = *(const float4*)(lng + c0 + 4);
        float4 b0 = *(const float4*)(lnb + c0), b1 = *(const float4*)(lnb + c0 + 4);
        const float gg[8] = {g0.x, g0.y, g0.z, g0.w, g1.x, g1.y, g1.z, g1.w};
        const float bb[8] = {b0.x, b0.y, b0.z, b0.w, b1.x, b1.y, b1.z, b1.w};
        s16x8 o;
        #pragma unroll
        for (int i = 0; i < 8; ++i) o[i] = f2bf((v[i] - mu) * rstd * gg[i] + bb[i]);
        *(s16x8*)((char*)xb + rloc * 1024 + ((c0 * 2) ^ ((rloc & 7) << 4))) = o;
    }
    __syncthreads();

    // --- Phase 2: W1 GEMM (K=512) + GELU -> hb
    {
        s16x8 afr[16];
        #pragma unroll
        for (int ks = 0; ks < 16; ++ks)
            afr[ks] = *(const s16x8*)((char*)xb + l15 * 1024 + (((ks * 32 + lg * 8) * 2) ^ axor));
        #pragma unroll
        for (int nt = 0; nt < 4; ++nt) {
            const int col = w * 64 + nt * 16 + l15;
            f32x4 acc = {0.f, 0.f, 0.f, 0.f};
            const short* bp_ = Wd1T + (size_t)col * 512 + lg * 8;
            #pragma unroll
            for (int ks = 0; ks < 16; ++ks)
                acc = MFMA(afr[ks], *(const s16x8*)(bp_ + ks * 32), acc);
            const float bv = bd1[col];
            #pragma unroll
            for (int j = 0; j < 4; ++j) {
                const int row = lg * 4 + j;
                *(short*)((char*)hb + row * 512 + ((col * 2) ^ ((row & 7) << 4)))
                    = f2bf(gelu_f(acc[j] + bv));
            }
        }
    }
    __syncthreads();

    // --- Phase 3: prev load + W2 GEMM -> dec; build concat(prev,dec)
    {
        const int prow = t >> 4, pc = (t & 15) * 16;
        const float* pp = prev + (size_t)(r0 + prow) * D + pc;
        #pragma unroll
        for (int g = 0; g < 2; ++g) {
            float4 x0 = *(const float4*)(pp + g * 8), x1 = *(const float4*)(pp + g * 8 + 4);
            const float pv[8] = {x0.x, x0.y, x0.z, x0.w, x1.x, x1.y, x1.z, x1.w};
            s16x8 v;
            #pragma unroll
            for (int i = 0; i < 8; ++i) { xf[prow][pc + g * 8 + i] = pv[i]; v[i] = f2bf(pv[i]); }
            *(s16x8*)((char*)xb + prow * 1024 + (((pc + g * 8) * 2) ^ ((prow & 7) << 4))) = v;
        }
        s16x8 af2[8];
        #pragma unroll
        for (int ks = 0; ks < 8; ++ks)
            af2[ks] = *(const s16x8*)((char*)hb + l15 * 512 + (((ks * 32 + lg * 8) * 2) ^ axor));
        #pragma unroll
        for (int nt = 0; nt < 4; ++nt) {
            const int col = w * 64 + nt * 16 + l15;
            f32x4 acc = {0.f, 0.f, 0.f, 0.f};
            const short* bp_ = Wd2T + (size_t)col * 256 + lg * 8;
            #pragma unroll
            for (int ks = 0; ks < 8; ++ks)
                acc = MFMA(af2[ks], *(const s16x8*)(bp_ + ks * 32), acc);
            const float bv = bd2[col];
            #pragma unroll
            for (int j = 0; j < 4; ++j) {
                const int row = lg * 4 + j;
                const int n = (r0 + row) & (NAG - 1);
                const float d = (acc[j] + bv) * (1.0f + 0.1f * pers[(size_t)n * D + col]);
                xf[row][D + col] = d;
                *(short*)((char*)xb + row * 1024 + (((D + col) * 2) ^ ((row & 7) << 4))) = f2bf(d);
            }
        }
    }
    __syncthreads();

    // --- Phase 4: gate GEMM (K=512) + blend
    float sv[4][4];
    {
        s16x8 af3[16];
        #pragma unroll
        for (int ks = 0; ks < 16; ++ks)
            af3[ks] = *(const s16x8*)((char*)xb + l15 * 1024 + (((ks * 32 + lg * 8) * 2) ^ axor));
        #pragma unroll
        for (int nt = 0; nt < 4; ++nt) {
            const int col = w * 64 + nt * 16 + l15;
            f32x4 acc = {0.f, 0.f, 0.f, 0.f};
            const short* bp_ = WgT + (size_t)col * 512 + lg * 8;
            #pragma unroll
            for (int ks = 0; ks < 16; ++ks)
                acc = MFMA(af3[ks], *(const s16x8*)(bp_ + ks * 32), acc);
            const float bgv = bg[col];
            #pragma unroll
            for (int j = 0; j < 4; ++j) {
                const int row = lg * 4 + j;
                const float g = sigmoid_f(acc[j] + bgv);
                sv[nt][j] = g * xf[row][D + col] + (1.0f - g) * xf[row][col];
            }
        }
    }

    // --- Phase 5: LN(256) cross-wave + st/stbf + mem-dot
    float rs[4], rq[4];
    #pragma unroll
    for (int j = 0; j < 4; ++j) {
        float a = sv[0][j] + sv[1][j] + sv[2][j] + sv[3][j];
        float q = sv[0][j] * sv[0][j] + sv[1][j] * sv[1][j]
                + sv[2][j] * sv[2][j] + sv[3][j] * sv[3][j];
        #pragma unroll
        for (int m = 1; m < 16; m <<= 1) { a += __shfl_xor(a, m); q += __shfl_xor(q, m); }
        rs[j] = a; rq[j] = q;
    }
    if (l15 == 0) {
        #pragma unroll
        for (int j = 0; j < 4; ++j) { red1[w][lg * 4 + j] = rs[j]; red2[w][lg * 4 + j] = rq[j]; }
    }
    __syncthreads();

    float md[4];
    #pragma unroll
    for (int j = 0; j < 4; ++j) {
        const int lr = lg * 4 + j;
        const float tot  = red1[0][lr] + red1[1][lr] + red1[2][lr] + red1[3][lr];
        const float tot2 = red2[0][lr] + red2[1][lr] + red2[2][lr] + red2[3][lr];
        const float mu = tot * (1.0f / 256.0f);
        const float var = tot2 * (1.0f / 256.0f) - mu * mu;
        const float rstd = rsqrtf(var + 1e-5f);
        float m_ = 0.f;
        #pragma unroll
        for (int nt = 0; nt < 4; ++nt) {
            const int col = w * 64 + nt * 16 + l15;
            const float ns = (sv[nt][j] - mu) * rstd * lnog[col] + lnob[col];
            out_st[(size_t)(r0 + lr) * D + col] = ns;
            stbf[(size_t)(r0 + lr) * D + col] = f2bf(ns);
            *(short*)((char*)hb + lr * 512 + ((col * 2) ^ ((lr & 7) << 4))) = f2bf(ns);
            m_ += ns * Wm[col];
        }
        #pragma unroll
        for (int m = 1; m < 16; m <<= 1) m_ += __shfl_xor(m_, m);
        md[j] = m_;
    }
    __syncthreads();
    if (l15 == 0) {
        #pragma unroll
        for (int j = 0; j < 4; ++j) red1[w][lg * 4 + j] = md[j];
    }
    __syncthreads();

    // --- Phase 6: mem_gate final + act GEMM (K=256)
    if (w == 0 && l15 == 0) {
        #pragma unroll
        for (int j = 0; j < 4; ++j) {
            const int lr = lg * 4 + j;
            const float tot = red1[0][lr] + red1[1][lr] + red1[2][lr] + red1[3][lr];
            float dotv = 0.f;
            for (int i = 0; i < QSPL; ++i) dotv += dot_part[i * NROWS + r0 + lr];
            out_mg[r0 + lr] = sigmoid_f(tot + dotv + bm[0]);
        }
    }
    {
        s16x8 af4[8];
        #pragma unroll
        for (int ks = 0; ks < 8; ++ks)
            af4[ks] = *(const s16x8*)((char*)hb + l15 * 512 + (((ks * 32 + lg * 8) * 2) ^ axor));
        #pragma unroll
        for (int nt = 0; nt < 4; ++nt) {
            const int col = w * 64 + nt * 16 + l15;
            f32x4 acc = {0.f, 0.f, 0.f, 0.f};
            const short* bp_ = WaT + (size_t)col * 256 + lg * 8;
            #pragma unroll
            for (int ks = 0; ks < 8; ++ks)
                acc = MFMA(af4[ks], *(const s16x8*)(bp_ + ks * 32), acc);
            const float bav = ba[col];
            #pragma unroll
            for (int j = 0; j < 4; ++j)
                out_act[(size_t)(r0 + lg * 4 + j) * D + col] = acc[j] + bav;
        }
    }
}

// ------------------------------------------------ exp GEMM + episodic write (R12-proven, ESPL=32)
__global__ __launch_bounds__(256) void k_exp(
    const short* __restrict__ stbf, const short* __restrict__ WhT,
    const float* __restrict__ bh, const float* __restrict__ ep,
    const float* __restrict__ keyf, const float* __restrict__ mg,
    float* __restrict__ out_exp, float* __restrict__ out_nep)
{
    __shared__ __align__(16) short sts[64 * 256];
    __shared__ __align__(16) short whs[16 * 256];
    const int t = threadIdx.x, l = t & 63, w = t >> 6;
    const int l15 = l & 15, lg = l >> 4;
    const int r0 = blockIdx.y * 64;
    const int hb0 = blockIdx.x * (HH / ESPL);
    const int axor = (l15 & 7) << 4;

    for (int p = 0; p < 8; ++p) {
        int e = p * 2048 + t * 8; int r = e >> 8, k = e & 255;
        s16x8 v = *(const s16x8*)(stbf + (size_t)(r0 + r) * 256 + k);
        *(s16x8*)((char*)sts + r * 512 + ((k * 2) ^ ((r & 7) << 4))) = v;
    }
    float mgv[4];
    #pragma unroll
    for (int j = 0; j < 4; ++j) mgv[j] = mg[r0 + w * 16 + lg * 4 + j];
    __syncthreads();

    const int arow = (w * 16 + l15) * 512;
    s16x8 afr[8];
    #pragma unroll
    for (int ks = 0; ks < 8; ++ks)
        afr[ks] = *(const s16x8*)((const char*)sts + arow + ((ks * 64 + lg * 16) ^ axor));

    for (int nt = 0; nt < (HH / ESPL) / 16; ++nt) {
        const int hg0 = hb0 + nt * 16;
        for (int p = 0; p < 2; ++p) {
            int e = p * 2048 + t * 8; int hh = e >> 8, k = e & 255;
            s16x8 v = *(const s16x8*)(WhT + (size_t)(hg0 + hh) * 256 + k);
            *(s16x8*)((char*)whs + hh * 512 + ((k * 2) ^ ((hh & 7) << 4))) = v;
        }
        __syncthreads();

        f32x4 acc = {0.f, 0.f, 0.f, 0.f};
        #pragma unroll
        for (int ks = 0; ks < 8; ++ks) {
            s16x8 b = *(const s16x8*)((const char*)whs + l15 * 512 + ((ks * 64 + lg * 16) ^ axor));
            acc = MFMA(afr[ks], b, acc);
        }
        const int h = hg0 + l15;
        const float bhv = bh[h];
        #pragma unroll
        for (int j = 0; j < 4; ++j) {
            const int row = r0 + w * 16 + lg * 4 + j;
            const int n = row & (NAG - 1);
            const float q = tanhf(acc[j] + bhv);
            const size_t idx = (size_t)row * HH + h;
            out_exp[idx] = q;
            out_nep[idx] = 0.95f * ep[idx] + mgv[j] * q * keyf[(size_t)n * HH + h];
        }
        __syncthreads();
    }
}

// ----------------------------------------------------------------
extern "C" void kernel_launch(void* const* d_in, const int* in_sizes, int n_in,
                              void* d_out, int out_size, void* d_ws, size_t ws_size,
                              hipStream_t stream)
{
    const float* sig   = (const float*)d_in[0];
    const float* act   = (const float*)d_in[1];
    const float* ep    = (const float*)d_in[2];
    const float* cr    = (const float*)d_in[3];
    const float* prev  = (const float*)d_in[4];
    const float* lnpg  = (const float*)d_in[6];
    const float* lnpb  = (const float*)d_in[7];
    const float* Wp    = (const float*)d_in[8];
    const float* bp    = (const float*)d_in[9];
    const float* lndg  = (const float*)d_in[10];
    const float* lndb  = (const float*)d_in[11];
    const float* Wd1   = (const float*)d_in[12];
    const float* bd1   = (const float*)d_in[13];
    const float* Wd2   = (const float*)d_in[14];
    const float* bd2   = (const float*)d_in[15];
    const float* Wg    = (const float*)d_in[16];
    const float* bg    = (const float*)d_in[17];
    const float* Wa    = (const float*)d_in[18];
    const float* ba    = (const float*)d_in[19];
    const float* Wh    = (const float*)d_in[20];
    const float* bh    = (const float*)d_in[21];
    const float* Wf    = (const float*)d_in[22];
    const float* bfrom = (const float*)d_in[23];
    const float* Wm    = (const float*)d_in[24];
    const float* bm    = (const float*)d_in[25];
    const float* pers  = (const float*)d_in[26];
    const float* chr   = (const float*)d_in[27];
    const float* key   = (const float*)d_in[28];
    const float* lnog  = (const float*)d_in[29];
    const float* lnob  = (const float*)d_in[30];

    float* outp    = (float*)d_out;
    float* out_act = outp;                  // (B,N,D)
    float* out_st  = outp + 524288;         // (B,N,D)
    float* out_nep = outp + 1048576;        // (B,N,H)
    float* out_exp = outp + 17825792;       // (B,N,H)
    float* out_mg  = outp + 34603008;       // (B,N)

    // out_nep region (dead until k_exp writes it; k_exp doesn't read these)
    short* ebf   = (short*)out_nep;               // 2048x8192 bf16 (32 MB)
    float* rpart = out_nep + 8388608;             // 16*2048*256 f32 (32 MB) — fills region exactly

    // out_exp region (dead until k_exp writes it)
    float* base = out_exp;
    short* WpT      = (short*)(base);             // 512x256
    short* Wd1T     = (short*)(base + 65536);     // 512x256
    short* Wd2T     = (short*)(base + 131072);    // 256x256
    short* WgT      = (short*)(base + 163840);    // 512x256
    short* WaT      = (short*)(base + 229376);    // 256x256
    short* WfT      = (short*)(base + 262144);    // 256x8192
    float* sim_part = base + 1310720;             // 32*2048
    float* dot_part = base + 1376256;             // 32*2048 -> ends 1441792

    // d_ws (~6.3 MB, validated)
    short* WhT    = (short*)d_ws;            // 8192x256 bf16
    short* percbf = WhT + 2097152;           // 2048x256 bf16
    short* stbf   = percbf + 524288;         // 2048x256 bf16

    k_prep_weights<<<dim3(1152), dim3(256), 0, stream>>>(
        Wh, Wf, Wp, Wd1, Wd2, Wg, Wa,
        WhT, WfT, WpT, Wd1T, Wd2T, WgT, WaT);

    k_prep_e<<<dim3(2048), dim3(256), 0, stream>>>(ep, cr, ebf);

    k_perc_mega<<<dim3(NROWS / 16), dim3(256), 0, stream>>>(
        sig, act, pers, chr, lnpg, lnpb, WpT, bp, percbf);

    k_query<<<dim3(QSPL, NROWS / 64), dim3(256), 0, stream>>>(
        percbf, WhT, bh, ebf, key, Wm, sim_part, dot_part);

    k_recall<<<dim3(KSPL, NROWS / 64), dim3(256), 0, stream>>>(ebf, WfT, rpart);

    k_dec_mega<<<dim3(NROWS / 16), dim3(256), 0, stream>>>(
        percbf, rpart, bfrom, sim_part, lndg, lndb, Wd1T, bd1, Wd2T, bd2,
        pers, prev, WgT, bg, lnog, lnob, WaT, ba, Wm, bm, dot_part,
        out_act, out_st, stbf, out_mg);

    k_exp<<<dim3(ESPL, NROWS / 64), dim3(256), 0, stream>>>(
        stbf, WhT, bh, ep, key, out_mg, out_exp, out_nep);
}

// Round 14
// 200.176 us; speedup vs baseline: 1.1475x; 1.1475x over previous
//
#include <hip/hip_runtime.h>
#include <hip/hip_bf16.h>
#include <math.h>

#define D     256
#define D2    512
#define HH    8192
#define NAG   64
#define NROWS 2048
#define KSPL  16    // recall K-split
#define QSPL  32    // query h-split
#define ESPL  32    // exp h-split

typedef short  s16x8 __attribute__((ext_vector_type(8)));
typedef __bf16 b16x8 __attribute__((ext_vector_type(8)));
typedef float  f32x4 __attribute__((ext_vector_type(4)));

template <typename T>
__device__ __forceinline__ auto mfma_try(T a, T b, f32x4 c, int)
    -> decltype(__builtin_amdgcn_mfma_f32_16x16x32_bf16(a, b, c, 0, 0, 0))
{ return __builtin_amdgcn_mfma_f32_16x16x32_bf16(a, b, c, 0, 0, 0); }

template <typename T>
__device__ __forceinline__ f32x4 mfma_try(T a, T b, f32x4 c, long)
{
    return __builtin_amdgcn_mfma_f32_16x16x32_bf16(
        __builtin_bit_cast(b16x8, a), __builtin_bit_cast(b16x8, b), c, 0, 0, 0);
}

__device__ __forceinline__ f32x4 MFMA(s16x8 a, s16x8 b, f32x4 c)
{ return mfma_try(a, b, c, 0); }

__device__ __forceinline__ float gelu_f(float x) {
    return 0.5f * x * (1.0f + erff(x * 0.70710678118654752440f));
}
__device__ __forceinline__ float sigmoid_f(float x) {
    return 1.0f / (1.0f + expf(-x));
}
__device__ __forceinline__ short f2bf(float x) {
    __hip_bfloat16 h(x);
    return __builtin_bit_cast(short, h);
}
__device__ __forceinline__ float bf2f(short s) {
    unsigned u = ((unsigned)(unsigned short)s) << 16;
    return __builtin_bit_cast(float, u);
}

// ------------------------------------------------ transpose f32 -> bf16
__device__ __forceinline__ void transpose_body(
    const float* __restrict__ src, short* __restrict__ dst, int R, int C, int lb)
{
    __shared__ float tl[64][65];
    const int t = threadIdx.x;
    const int Ctiles = C >> 6;
    const int bc = lb % Ctiles, br = lb / Ctiles;
    const int r0 = br * 64, c0 = bc * 64;
    for (int p = 0; p < 16; ++p) {
        int e = p * 256 + t; int i = e >> 6, j = e & 63;
        tl[i][j] = src[(size_t)(r0 + i) * C + c0 + j];
    }
    __syncthreads();
    for (int p = 0; p < 16; ++p) {
        int e = p * 256 + t; int jj = e >> 6, ii = e & 63;
        dst[(size_t)(c0 + jj) * R + r0 + ii] = f2bf(tl[ii][jj]);
    }
}

__global__ __launch_bounds__(256) void k_prep_weights(
    const float* __restrict__ Wh, const float* __restrict__ Wf,
    const float* __restrict__ Wp, const float* __restrict__ Wd1,
    const float* __restrict__ Wd2, const float* __restrict__ Wg,
    const float* __restrict__ Wa,
    short* __restrict__ WhT, short* __restrict__ WfT,
    short* __restrict__ WpT, short* __restrict__ Wd1T,
    short* __restrict__ Wd2T, short* __restrict__ WgT,
    short* __restrict__ WaT)
{
    const int b = blockIdx.x;
    if      (b < 512)  { transpose_body(Wh,  WhT,  256,  HH, b);        }
    else if (b < 1024) { transpose_body(Wf,  WfT,  HH,  256, b - 512);  }
    else if (b < 1056) { transpose_body(Wp,  WpT,  512, 256, b - 1024); }
    else if (b < 1088) { transpose_body(Wd1, Wd1T, 512, 256, b - 1056); }
    else if (b < 1104) { transpose_body(Wd2, Wd2T, 256, 256, b - 1088); }
    else if (b < 1136) { transpose_body(Wg,  WgT,  512, 256, b - 1104); }
    else               { transpose_body(Wa,  WaT,  256, 256, b - 1136); }
}

// ------------------------------------------------ pure streaming: ebf = bf16(ep+cr)
__global__ __launch_bounds__(256) void k_prep_e(
    const float* __restrict__ ep, const float* __restrict__ cr,
    short* __restrict__ ebf)
{
    const size_t i0 = ((size_t)blockIdx.x * 256 + threadIdx.x) * 8;
    const size_t stride = (size_t)gridDim.x * 256 * 8;
    for (size_t i = i0; i < (size_t)NROWS * HH; i += stride) {
        float4 e0 = *(const float4*)(ep + i), e1 = *(const float4*)(ep + i + 4);
        float4 c0 = *(const float4*)(cr + i), c1 = *(const float4*)(cr + i + 4);
        s16x8 ev;
        ev[0] = f2bf(e0.x + c0.x); ev[1] = f2bf(e0.y + c0.y);
        ev[2] = f2bf(e0.z + c0.z); ev[3] = f2bf(e0.w + c0.w);
        ev[4] = f2bf(e1.x + c1.x); ev[5] = f2bf(e1.y + c1.y);
        ev[6] = f2bf(e1.z + c1.z); ev[7] = f2bf(e1.w + c1.w);
        *(s16x8*)(ebf + i) = ev;
    }
}

// ------------------------------------------------ perception mega: LN + Wp GEMM + GELU
__global__ __launch_bounds__(256) void k_perc_mega(
    const float* __restrict__ sig, const float* __restrict__ act,
    const float* __restrict__ pers, const float* __restrict__ chr,
    const float* __restrict__ lng, const float* __restrict__ lnb,
    const short* __restrict__ WpT, const float* __restrict__ bp,
    short* __restrict__ percbf)
{
    __shared__ __align__(16) short xb[16 * 512];
    const int t = threadIdx.x, l = t & 63, w = t >> 6;
    const int l15 = l & 15, lg = l >> 4;
    const int r0 = blockIdx.x * 16;
    const int axor = (l15 & 7) << 4;

    for (int rr = 0; rr < 4; ++rr) {
        const int rloc = w * 4 + rr, row = r0 + rloc;
        const int n = row & (NAG - 1);
        const int c0 = l * 8;
        float v[8];
        if (l < 32) {
            const float* sp = sig  + (size_t)row * D + c0;
            const float* pp = pers + (size_t)n * D + c0;
            const float* cp = chr  + (size_t)n * D + c0;
            float4 s0 = *(const float4*)sp, s1 = *(const float4*)(sp + 4);
            float4 p0 = *(const float4*)pp, p1 = *(const float4*)(pp + 4);
            float4 q0 = *(const float4*)cp, q1 = *(const float4*)(cp + 4);
            v[0] = s0.x * (1.f + 0.1f * (p0.x + 0.3f * q0.x));
            v[1] = s0.y * (1.f + 0.1f * (p0.y + 0.3f * q0.y));
            v[2] = s0.z * (1.f + 0.1f * (p0.z + 0.3f * q0.z));
            v[3] = s0.w * (1.f + 0.1f * (p0.w + 0.3f * q0.w));
            v[4] = s1.x * (1.f + 0.1f * (p1.x + 0.3f * q1.x));
            v[5] = s1.y * (1.f + 0.1f * (p1.y + 0.3f * q1.y));
            v[6] = s1.z * (1.f + 0.1f * (p1.z + 0.3f * q1.z));
            v[7] = s1.w * (1.f + 0.1f * (p1.w + 0.3f * q1.w));
        } else {
            const float* ap = act + (size_t)row * D + (c0 - D);
            float4 a0 = *(const float4*)ap, a1 = *(const float4*)(ap + 4);
            v[0] = a0.x; v[1] = a0.y; v[2] = a0.z; v[3] = a0.w;
            v[4] = a1.x; v[5] = a1.y; v[6] = a1.z; v[7] = a1.w;
        }
        float s = 0.f;
        #pragma unroll
        for (int i = 0; i < 8; ++i) s += v[i];
        #pragma unroll
        for (int m = 1; m < 64; m <<= 1) s += __shfl_xor(s, m);
        const float mu = s * (1.0f / 512.0f);
        float q = 0.f;
        #pragma unroll
        for (int i = 0; i < 8; ++i) { float c = v[i] - mu; q += c * c; }
        #pragma unroll
        for (int m = 1; m < 64; m <<= 1) q += __shfl_xor(q, m);
        const float rstd = rsqrtf(q * (1.0f / 512.0f) + 1e-5f);
        float4 g0 = *(const float4*)(lng + c0), g1 = *(const float4*)(lng + c0 + 4);
        float4 b0 = *(const float4*)(lnb + c0), b1 = *(const float4*)(lnb + c0 + 4);
        const float gg[8] = {g0.x, g0.y, g0.z, g0.w, g1.x, g1.y, g1.z, g1.w};
        const float bb[8] = {b0.x, b0.y, b0.z, b0.w, b1.x, b1.y, b1.z, b1.w};
        s16x8 o;
        #pragma unroll
        for (int i = 0; i < 8; ++i) o[i] = f2bf((v[i] - mu) * rstd * gg[i] + bb[i]);
        *(s16x8*)((char*)xb + rloc * 1024 + ((c0 * 2) ^ ((rloc & 7) << 4))) = o;
    }
    __syncthreads();

    s16x8 afr[16];
    #pragma unroll
    for (int ks = 0; ks < 16; ++ks)
        afr[ks] = *(const s16x8*)((char*)xb + l15 * 1024 + (((ks * 32 + lg * 8) * 2) ^ axor));
    #pragma unroll
    for (int nt = 0; nt < 4; ++nt) {
        const int col = w * 64 + nt * 16 + l15;
        f32x4 acc = {0.f, 0.f, 0.f, 0.f};
        const short* bp_ = WpT + (size_t)col * 512 + lg * 8;
        #pragma unroll
        for (int ks = 0; ks < 16; ++ks)
            acc = MFMA(afr[ks], *(const s16x8*)(bp_ + ks * 32), acc);
        const float bv = bp[col];
        #pragma unroll
        for (int j = 0; j < 4; ++j)
            percbf[(size_t)(r0 + lg * 4 + j) * D + col] = f2bf(gelu_f(acc[j] + bv));
    }
}

// ------------------------------------------------ query (proven structure, QSPL=32)
__global__ __launch_bounds__(256) void k_query(
    const short* __restrict__ percbf, const short* __restrict__ WhT,
    const float* __restrict__ bh, const short* __restrict__ ebf,
    const float* __restrict__ keyf, const float* __restrict__ Wm,
    float* __restrict__ sim_part, float* __restrict__ dot_part)
{
    __shared__ __align__(16) short percs[64 * 256];
    __shared__ __align__(16) short whs[16 * 256];
    __shared__ __align__(16) short es[64 * 20];
    __shared__ __align__(16) short ks2[64 * 20];
    const int t = threadIdx.x;
    const int l = t & 63, w = t >> 6;
    const int l15 = l & 15, lg = l >> 4;
    const int r0 = blockIdx.y * 64;
    const int hb0 = blockIdx.x * (HH / QSPL);
    const int axor = (l15 & 7) << 4;

    for (int p = 0; p < 8; ++p) {
        int e = p * 2048 + t * 8; int r = e >> 8, k = e & 255;
        s16x8 v = *(const s16x8*)(percbf + (size_t)(r0 + r) * 256 + k);
        *(s16x8*)((char*)percs + r * 512 + ((k * 2) ^ ((r & 7) << 4))) = v;
    }
    __syncthreads();

    const int arow = (w * 16 + l15) * 512;
    s16x8 afr[8];
    #pragma unroll
    for (int ks = 0; ks < 8; ++ks)
        afr[ks] = *(const s16x8*)((const char*)percs + arow + ((ks * 64 + lg * 16) ^ axor));

    float psim[4] = {0, 0, 0, 0}, pdot[4] = {0, 0, 0, 0};

    for (int nt = 0; nt < (HH / QSPL) / 16; ++nt) {
        const int hg0 = hb0 + nt * 16;
        for (int p = 0; p < 2; ++p) {
            int e = p * 2048 + t * 8; int hh = e >> 8, k = e & 255;
            s16x8 v = *(const s16x8*)(WhT + (size_t)(hg0 + hh) * 256 + k);
            *(s16x8*)((char*)whs + hh * 512 + ((k * 2) ^ ((hh & 7) << 4))) = v;
        }
        {
            int e = t * 4; int r = e >> 4, hh = e & 15;
            short4 v = *(const short4*)(ebf + (size_t)(r0 + r) * HH + hg0 + hh);
            es[r * 20 + hh + 0] = v.x; es[r * 20 + hh + 1] = v.y;
            es[r * 20 + hh + 2] = v.z; es[r * 20 + hh + 3] = v.w;
            float4 kv = *(const float4*)(keyf + (size_t)r * HH + hg0 + hh);
            ks2[r * 20 + hh + 0] = f2bf(kv.x); ks2[r * 20 + hh + 1] = f2bf(kv.y);
            ks2[r * 20 + hh + 2] = f2bf(kv.z); ks2[r * 20 + hh + 3] = f2bf(kv.w);
        }
        __syncthreads();

        f32x4 acc = {0.f, 0.f, 0.f, 0.f};
        #pragma unroll
        for (int ks = 0; ks < 8; ++ks) {
            s16x8 b = *(const s16x8*)((const char*)whs + l15 * 512 + ((ks * 64 + lg * 16) ^ axor));
            acc = MFMA(afr[ks], b, acc);
        }
        const int h = hg0 + l15;
        const float bhv = bh[h];
        const float wmv = Wm[D + h];
        #pragma unroll
        for (int j = 0; j < 4; ++j) {
            const int rl = w * 16 + lg * 4 + j;
            const float q = tanhf(acc[j] + bhv);
            psim[j] += q * bf2f(es[rl * 20 + l15]) * bf2f(ks2[rl * 20 + l15]);
            pdot[j] += q * wmv;
        }
        __syncthreads();
    }

    #pragma unroll
    for (int j = 0; j < 4; ++j) {
        float s = psim[j], d = pdot[j];
        for (int m = 1; m < 16; m <<= 1) { s += __shfl_xor(s, m); d += __shfl_xor(d, m); }
        if (l15 == 0) {
            const int row = r0 + w * 16 + lg * 4 + j;
            sim_part[blockIdx.x * NROWS + row] = s;
            dot_part[blockIdx.x * NROWS + row] = d;
        }
    }
}

// ------------------------------------------------ recall GEMM (proven, KSPL=16)
__global__ __launch_bounds__(256) void k_recall(
    const short* __restrict__ ebf, const short* __restrict__ WfT,
    float* __restrict__ rpart)
{
    __shared__ __align__(16) short as_[64 * 64];
    __shared__ __align__(16) short bs[256 * 64];
    const int t = threadIdx.x, l = t & 63, w = t >> 6;
    const int l15 = l & 15, lg = l >> 4;
    const int r0 = blockIdx.y * 64;
    const int kc0 = blockIdx.x * (HH / KSPL);
    const int axor = (l15 & 7) << 4;

    f32x4 acc[16];
    #pragma unroll
    for (int i = 0; i < 16; ++i) acc[i] = {0.f, 0.f, 0.f, 0.f};

    for (int kk = 0; kk < HH / KSPL; kk += 64) {
        __syncthreads();
        for (int p = 0; p < 2; ++p) {
            int e = p * 2048 + t * 8; int r = e >> 6, k = e & 63;
            s16x8 v = *(const s16x8*)(ebf + (size_t)(r0 + r) * HH + kc0 + kk + k);
            *(s16x8*)((char*)as_ + r * 128 + ((k * 2) ^ ((r & 7) << 4))) = v;
        }
        for (int p = 0; p < 8; ++p) {
            int e = p * 2048 + t * 8; int n = e >> 6, k = e & 63;
            s16x8 v = *(const s16x8*)(WfT + (size_t)n * HH + kc0 + kk + k);
            *(s16x8*)((char*)bs + n * 128 + ((k * 2) ^ ((n & 7) << 4))) = v;
        }
        __syncthreads();
        const int abase = (w * 16 + l15) * 128;
        s16x8 a0 = *(const s16x8*)((const char*)as_ + abase + ((lg * 16) ^ axor));
        s16x8 a1 = *(const s16x8*)((const char*)as_ + abase + ((64 + lg * 16) ^ axor));
        #pragma unroll
        for (int nt = 0; nt < 16; ++nt) {
            const int bbase = (nt * 16 + l15) * 128;
            s16x8 b0 = *(const s16x8*)((const char*)bs + bbase + ((lg * 16) ^ axor));
            s16x8 b1 = *(const s16x8*)((const char*)bs + bbase + ((64 + lg * 16) ^ axor));
            acc[nt] = MFMA(a0, b0, acc[nt]);
            acc[nt] = MFMA(a1, b1, acc[nt]);
        }
    }
    #pragma unroll
    for (int nt = 0; nt < 16; ++nt) {
        #pragma unroll
        for (int j = 0; j < 4; ++j) {
            const int row = r0 + w * 16 + lg * 4 + j;
            rpart[((size_t)blockIdx.x * NROWS + row) * D + nt * 16 + l15] = acc[nt][j];
        }
    }
}

// ------------------------------------------------ decision mega: LN+W1+GELU+W2+gate+LN+act+mem_gate
__global__ __launch_bounds__(256) void k_dec_mega(
    const short* __restrict__ percbf, const float* __restrict__ rpart,
    const float* __restrict__ bfrom, const float* __restrict__ sim_part,
    const float* __restrict__ lng, const float* __restrict__ lnb,
    const short* __restrict__ Wd1T, const float* __restrict__ bd1,
    const short* __restrict__ Wd2T, const float* __restrict__ bd2,
    const float* __restrict__ pers, const float* __restrict__ prev,
    const short* __restrict__ WgT, const float* __restrict__ bg,
    const float* __restrict__ lnog, const float* __restrict__ lnob,
    const short* __restrict__ WaT, const float* __restrict__ ba,
    const float* __restrict__ Wm, const float* __restrict__ bm,
    const float* __restrict__ dot_part,
    float* __restrict__ out_act, float* __restrict__ out_st,
    short* __restrict__ stbf, float* __restrict__ out_mg)
{
    __shared__ __align__(16) short xb[16 * 512];
    __shared__ __align__(16) short hb[16 * 256];
    __shared__ __align__(16) float xf[16][512];
    __shared__ float red1[4][16], red2[4][16];
    const int t = threadIdx.x, l = t & 63, w = t >> 6;
    const int l15 = l & 15, lg = l >> 4;
    const int r0 = blockIdx.x * 16;
    const int axor = (l15 & 7) << 4;

    // --- Phase 1: dec_in build + LN(512) -> xb
    for (int rr = 0; rr < 4; ++rr) {
        const int rloc = w * 4 + rr, row = r0 + rloc;
        float sr = (l < QSPL) ? sim_part[l * NROWS + row] : 0.f;
        #pragma unroll
        for (int m = 1; m < 32; m <<= 1) sr += __shfl_xor(sr, m);
        sr = __shfl(sr, 0);
        const float strength = sigmoid_f(sr * (1.0f / (float)HH));
        const int c0 = l * 8;
        float v[8];
        if (l < 32) {
            s16x8 pv = *(const s16x8*)(percbf + (size_t)row * D + c0);
            #pragma unroll
            for (int i = 0; i < 8; ++i) v[i] = bf2f(pv[i]);
        } else {
            const int c = c0 - D;
            float a[8] = {0, 0, 0, 0, 0, 0, 0, 0};
            for (int ks = 0; ks < KSPL; ++ks) {
                const float* rp = rpart + ((size_t)ks * NROWS + row) * D + c;
                float4 x0 = *(const float4*)rp, x1 = *(const float4*)(rp + 4);
                a[0] += x0.x; a[1] += x0.y; a[2] += x0.z; a[3] += x0.w;
                a[4] += x1.x; a[5] += x1.y; a[6] += x1.z; a[7] += x1.w;
            }
            float4 f0 = *(const float4*)(bfrom + c), f1 = *(const float4*)(bfrom + c + 4);
            const float fb[8] = {f0.x, f0.y, f0.z, f0.w, f1.x, f1.y, f1.z, f1.w};
            #pragma unroll
            for (int i = 0; i < 8; ++i) v[i] = (a[i] + fb[i]) * strength;
        }
        float s = 0.f;
        #pragma unroll
        for (int i = 0; i < 8; ++i) s += v[i];
        #pragma unroll
        for (int m = 1; m < 64; m <<= 1) s += __shfl_xor(s, m);
        const float mu = s * (1.0f / 512.0f);
        float q = 0.f;
        #pragma unroll
        for (int i = 0; i < 8; ++i) { float c = v[i] - mu; q += c * c; }
        #pragma unroll
        for (int m = 1; m < 64; m <<= 1) q += __shfl_xor(q, m);
        const float rstd = rsqrtf(q * (1.0f / 512.0f) + 1e-5f);
        float4 g0 = *(const float4*)(lng + c0), g1 = *(const float4*)(lng + c0 + 4);
        float4 b0 = *(const float4*)(lnb + c0), b1 = *(const float4*)(lnb + c0 + 4);
        const float gg[8] = {g0.x, g0.y, g0.z, g0.w, g1.x, g1.y, g1.z, g1.w};
        const float bb[8] = {b0.x, b0.y, b0.z, b0.w, b1.x, b1.y, b1.z, b1.w};
        s16x8 o;
        #pragma unroll
        for (int i = 0; i < 8; ++i) o[i] = f2bf((v[i] - mu) * rstd * gg[i] + bb[i]);
        *(s16x8*)((char*)xb + rloc * 1024 + ((c0 * 2) ^ ((rloc & 7) << 4))) = o;
    }
    __syncthreads();

    // --- Phase 2: W1 GEMM (K=512) + GELU -> hb
    {
        s16x8 afr[16];
        #pragma unroll
        for (int ks = 0; ks < 16; ++ks)
            afr[ks] = *(const s16x8*)((char*)xb + l15 * 1024 + (((ks * 32 + lg * 8) * 2) ^ axor));
        #pragma unroll
        for (int nt = 0; nt < 4; ++nt) {
            const int col = w * 64 + nt * 16 + l15;
            f32x4 acc = {0.f, 0.f, 0.f, 0.f};
            const short* bp_ = Wd1T + (size_t)col * 512 + lg * 8;
            #pragma unroll
            for (int ks = 0; ks < 16; ++ks)
                acc = MFMA(afr[ks], *(const s16x8*)(bp_ + ks * 32), acc);
            const float bv = bd1[col];
            #pragma unroll
            for (int j = 0; j < 4; ++j) {
                const int row = lg * 4 + j;
                *(short*)((char*)hb + row * 512 + ((col * 2) ^ ((row & 7) << 4)))
                    = f2bf(gelu_f(acc[j] + bv));
            }
        }
    }
    __syncthreads();

    // --- Phase 3: prev load + W2 GEMM -> dec; build concat(prev,dec)
    {
        const int prow = t >> 4, pc = (t & 15) * 16;
        const float* pp = prev + (size_t)(r0 + prow) * D + pc;
        #pragma unroll
        for (int g = 0; g < 2; ++g) {
            float4 x0 = *(const float4*)(pp + g * 8), x1 = *(const float4*)(pp + g * 8 + 4);
            const float pv[8] = {x0.x, x0.y, x0.z, x0.w, x1.x, x1.y, x1.z, x1.w};
            s16x8 v;
            #pragma unroll
            for (int i = 0; i < 8; ++i) { xf[prow][pc + g * 8 + i] = pv[i]; v[i] = f2bf(pv[i]); }
            *(s16x8*)((char*)xb + prow * 1024 + (((pc + g * 8) * 2) ^ ((prow & 7) << 4))) = v;
        }
        s16x8 af2[8];
        #pragma unroll
        for (int ks = 0; ks < 8; ++ks)
            af2[ks] = *(const s16x8*)((char*)hb + l15 * 512 + (((ks * 32 + lg * 8) * 2) ^ axor));
        #pragma unroll
        for (int nt = 0; nt < 4; ++nt) {
            const int col = w * 64 + nt * 16 + l15;
            f32x4 acc = {0.f, 0.f, 0.f, 0.f};
            const short* bp_ = Wd2T + (size_t)col * 256 + lg * 8;
            #pragma unroll
            for (int ks = 0; ks < 8; ++ks)
                acc = MFMA(af2[ks], *(const s16x8*)(bp_ + ks * 32), acc);
            const float bv = bd2[col];
            #pragma unroll
            for (int j = 0; j < 4; ++j) {
                const int row = lg * 4 + j;
                const int n = (r0 + row) & (NAG - 1);
                const float d = (acc[j] + bv) * (1.0f + 0.1f * pers[(size_t)n * D + col]);
                xf[row][D + col] = d;
                *(short*)((char*)xb + row * 1024 + (((D + col) * 2) ^ ((row & 7) << 4))) = f2bf(d);
            }
        }
    }
    __syncthreads();

    // --- Phase 4: gate GEMM (K=512) + blend
    float sv[4][4];
    {
        s16x8 af3[16];
        #pragma unroll
        for (int ks = 0; ks < 16; ++ks)
            af3[ks] = *(const s16x8*)((char*)xb + l15 * 1024 + (((ks * 32 + lg * 8) * 2) ^ axor));
        #pragma unroll
        for (int nt = 0; nt < 4; ++nt) {
            const int col = w * 64 + nt * 16 + l15;
            f32x4 acc = {0.f, 0.f, 0.f, 0.f};
            const short* bp_ = WgT + (size_t)col * 512 + lg * 8;
            #pragma unroll
            for (int ks = 0; ks < 16; ++ks)
                acc = MFMA(af3[ks], *(const s16x8*)(bp_ + ks * 32), acc);
            const float bgv = bg[col];
            #pragma unroll
            for (int j = 0; j < 4; ++j) {
                const int row = lg * 4 + j;
                const float g = sigmoid_f(acc[j] + bgv);
                sv[nt][j] = g * xf[row][D + col] + (1.0f - g) * xf[row][col];
            }
        }
    }

    // --- Phase 5: LN(256) cross-wave + st/stbf + mem-dot
    float rs[4], rq[4];
    #pragma unroll
    for (int j = 0; j < 4; ++j) {
        float a = sv[0][j] + sv[1][j] + sv[2][j] + sv[3][j];
        float q = sv[0][j] * sv[0][j] + sv[1][j] * sv[1][j]
                + sv[2][j] * sv[2][j] + sv[3][j] * sv[3][j];
        #pragma unroll
        for (int m = 1; m < 16; m <<= 1) { a += __shfl_xor(a, m); q += __shfl_xor(q, m); }
        rs[j] = a; rq[j] = q;
    }
    if (l15 == 0) {
        #pragma unroll
        for (int j = 0; j < 4; ++j) { red1[w][lg * 4 + j] = rs[j]; red2[w][lg * 4 + j] = rq[j]; }
    }
    __syncthreads();

    float md[4];
    #pragma unroll
    for (int j = 0; j < 4; ++j) {
        const int lr = lg * 4 + j;
        const float tot  = red1[0][lr] + red1[1][lr] + red1[2][lr] + red1[3][lr];
        const float tot2 = red2[0][lr] + red2[1][lr] + red2[2][lr] + red2[3][lr];
        const float mu = tot * (1.0f / 256.0f);
        const float var = tot2 * (1.0f / 256.0f) - mu * mu;
        const float rstd = rsqrtf(var + 1e-5f);
        float m_ = 0.f;
        #pragma unroll
        for (int nt = 0; nt < 4; ++nt) {
            const int col = w * 64 + nt * 16 + l15;
            const float ns = (sv[nt][j] - mu) * rstd * lnog[col] + lnob[col];
            __builtin_nontemporal_store(ns, &out_st[(size_t)(r0 + lr) * D + col]);
            stbf[(size_t)(r0 + lr) * D + col] = f2bf(ns);
            *(short*)((char*)hb + lr * 512 + ((col * 2) ^ ((lr & 7) << 4))) = f2bf(ns);
            m_ += ns * Wm[col];
        }
        #pragma unroll
        for (int m = 1; m < 16; m <<= 1) m_ += __shfl_xor(m_, m);
        md[j] = m_;
    }
    __syncthreads();
    if (l15 == 0) {
        #pragma unroll
        for (int j = 0; j < 4; ++j) red1[w][lg * 4 + j] = md[j];
    }
    __syncthreads();

    // --- Phase 6: mem_gate final + act GEMM (K=256)
    if (w == 0 && l15 == 0) {
        #pragma unroll
        for (int j = 0; j < 4; ++j) {
            const int lr = lg * 4 + j;
            const float tot = red1[0][lr] + red1[1][lr] + red1[2][lr] + red1[3][lr];
            float dotv = 0.f;
            for (int i = 0; i < QSPL; ++i) dotv += dot_part[i * NROWS + r0 + lr];
            out_mg[r0 + lr] = sigmoid_f(tot + dotv + bm[0]);
        }
    }
    {
        s16x8 af4[8];
        #pragma unroll
        for (int ks = 0; ks < 8; ++ks)
            af4[ks] = *(const s16x8*)((char*)hb + l15 * 512 + (((ks * 32 + lg * 8) * 2) ^ axor));
        #pragma unroll
        for (int nt = 0; nt < 4; ++nt) {
            const int col = w * 64 + nt * 16 + l15;
            f32x4 acc = {0.f, 0.f, 0.f, 0.f};
            const short* bp_ = WaT + (size_t)col * 256 + lg * 8;
            #pragma unroll
            for (int ks = 0; ks < 8; ++ks)
                acc = MFMA(af4[ks], *(const s16x8*)(bp_ + ks * 32), acc);
            const float bav = ba[col];
            #pragma unroll
            for (int j = 0; j < 4; ++j)
                __builtin_nontemporal_store(acc[j] + bav,
                    &out_act[(size_t)(r0 + lg * 4 + j) * D + col]);
        }
    }
}

// ------------------------------------------------ exp GEMM + episodic write (nt stores)
__global__ __launch_bounds__(256) void k_exp(
    const short* __restrict__ stbf, const short* __restrict__ WhT,
    const float* __restrict__ bh, const float* __restrict__ ep,
    const float* __restrict__ keyf, const float* __restrict__ mg,
    float* __restrict__ out_exp, float* __restrict__ out_nep)
{
    __shared__ __align__(16) short sts[64 * 256];
    __shared__ __align__(16) short whs[16 * 256];
    const int t = threadIdx.x, l = t & 63, w = t >> 6;
    const int l15 = l & 15, lg = l >> 4;
    const int r0 = blockIdx.y * 64;
    const int hb0 = blockIdx.x * (HH / ESPL);
    const int axor = (l15 & 7) << 4;

    for (int p = 0; p < 8; ++p) {
        int e = p * 2048 + t * 8; int r = e >> 8, k = e & 255;
        s16x8 v = *(const s16x8*)(stbf + (size_t)(r0 + r) * 256 + k);
        *(s16x8*)((char*)sts + r * 512 + ((k * 2) ^ ((r & 7) << 4))) = v;
    }
    float mgv[4];
    #pragma unroll
    for (int j = 0; j < 4; ++j) mgv[j] = mg[r0 + w * 16 + lg * 4 + j];
    __syncthreads();

    const int arow = (w * 16 + l15) * 512;
    s16x8 afr[8];
    #pragma unroll
    for (int ks = 0; ks < 8; ++ks)
        afr[ks] = *(const s16x8*)((const char*)sts + arow + ((ks * 64 + lg * 16) ^ axor));

    for (int nt = 0; nt < (HH / ESPL) / 16; ++nt) {
        const int hg0 = hb0 + nt * 16;
        for (int p = 0; p < 2; ++p) {
            int e = p * 2048 + t * 8; int hh = e >> 8, k = e & 255;
            s16x8 v = *(const s16x8*)(WhT + (size_t)(hg0 + hh) * 256 + k);
            *(s16x8*)((char*)whs + hh * 512 + ((k * 2) ^ ((hh & 7) << 4))) = v;
        }
        __syncthreads();

        f32x4 acc = {0.f, 0.f, 0.f, 0.f};
        #pragma unroll
        for (int ks = 0; ks < 8; ++ks) {
            s16x8 b = *(const s16x8*)((const char*)whs + l15 * 512 + ((ks * 64 + lg * 16) ^ axor));
            acc = MFMA(afr[ks], b, acc);
        }
        const int h = hg0 + l15;
        const float bhv = bh[h];
        #pragma unroll
        for (int j = 0; j < 4; ++j) {
            const int row = r0 + w * 16 + lg * 4 + j;
            const int n = row & (NAG - 1);
            const float q = tanhf(acc[j] + bhv);
            const size_t idx = (size_t)row * HH + h;
            __builtin_nontemporal_store(q, &out_exp[idx]);
            __builtin_nontemporal_store(
                0.95f * ep[idx] + mgv[j] * q * keyf[(size_t)n * HH + h], &out_nep[idx]);
        }
        __syncthreads();
    }
}

// ----------------------------------------------------------------
extern "C" void kernel_launch(void* const* d_in, const int* in_sizes, int n_in,
                              void* d_out, int out_size, void* d_ws, size_t ws_size,
                              hipStream_t stream)
{
    const float* sig   = (const float*)d_in[0];
    const float* act   = (const float*)d_in[1];
    const float* ep    = (const float*)d_in[2];
    const float* cr    = (const float*)d_in[3];
    const float* prev  = (const float*)d_in[4];
    const float* lnpg  = (const float*)d_in[6];
    const float* lnpb  = (const float*)d_in[7];
    const float* Wp    = (const float*)d_in[8];
    const float* bp    = (const float*)d_in[9];
    const float* lndg  = (const float*)d_in[10];
    const float* lndb  = (const float*)d_in[11];
    const float* Wd1   = (const float*)d_in[12];
    const float* bd1   = (const float*)d_in[13];
    const float* Wd2   = (const float*)d_in[14];
    const float* bd2   = (const float*)d_in[15];
    const float* Wg    = (const float*)d_in[16];
    const float* bg    = (const float*)d_in[17];
    const float* Wa    = (const float*)d_in[18];
    const float* ba    = (const float*)d_in[19];
    const float* Wh    = (const float*)d_in[20];
    const float* bh    = (const float*)d_in[21];
    const float* Wf    = (const float*)d_in[22];
    const float* bfrom = (const float*)d_in[23];
    const float* Wm    = (const float*)d_in[24];
    const float* bm    = (const float*)d_in[25];
    const float* pers  = (const float*)d_in[26];
    const float* chr   = (const float*)d_in[27];
    const float* key   = (const float*)d_in[28];
    const float* lnog  = (const float*)d_in[29];
    const float* lnob  = (const float*)d_in[30];

    float* outp    = (float*)d_out;
    float* out_act = outp;                  // (B,N,D)
    float* out_st  = outp + 524288;         // (B,N,D)
    float* out_nep = outp + 1048576;        // (B,N,H)
    float* out_exp = outp + 17825792;       // (B,N,H)
    float* out_mg  = outp + 34603008;       // (B,N)

    // out_nep region (dead until k_exp writes it; k_exp doesn't read these)
    short* ebf   = (short*)out_nep;               // 2048x8192 bf16 (32 MB)
    float* rpart = out_nep + 8388608;             // 16*2048*256 f32 (32 MB)

    // out_exp region (dead until k_exp writes it)
    float* base = out_exp;
    short* WpT      = (short*)(base);             // 512x256
    short* Wd1T     = (short*)(base + 65536);     // 512x256
    short* Wd2T     = (short*)(base + 131072);    // 256x256
    short* WgT      = (short*)(base + 163840);    // 512x256
    short* WaT      = (short*)(base + 229376);    // 256x256
    short* WfT      = (short*)(base + 262144);    // 256x8192
    float* sim_part = base + 1310720;             // 32*2048
    float* dot_part = base + 1376256;             // 32*2048 -> ends 1441792

    // d_ws (~6.3 MB, validated)
    short* WhT    = (short*)d_ws;            // 8192x256 bf16
    short* percbf = WhT + 2097152;           // 2048x256 bf16
    short* stbf   = percbf + 524288;         // 2048x256 bf16

    k_prep_weights<<<dim3(1152), dim3(256), 0, stream>>>(
        Wh, Wf, Wp, Wd1, Wd2, Wg, Wa,
        WhT, WfT, WpT, Wd1T, Wd2T, WgT, WaT);

    k_prep_e<<<dim3(2048), dim3(256), 0, stream>>>(ep, cr, ebf);

    k_perc_mega<<<dim3(NROWS / 16), dim3(256), 0, stream>>>(
        sig, act, pers, chr, lnpg, lnpb, WpT, bp, percbf);

    k_query<<<dim3(QSPL, NROWS / 64), dim3(256), 0, stream>>>(
        percbf, WhT, bh, ebf, key, Wm, sim_part, dot_part);

    k_recall<<<dim3(KSPL, NROWS / 64), dim3(256), 0, stream>>>(ebf, WfT, rpart);

    k_dec_mega<<<dim3(NROWS / 16), dim3(256), 0, stream>>>(
        percbf, rpart, bfrom, sim_part, lndg, lndb, Wd1T, bd1, Wd2T, bd2,
        pers, prev, WgT, bg, lnog, lnob, WaT, ba, Wm, bm, dot_part,
        out_act, out_st, stbf, out_mg);

    k_exp<<<dim3(ESPL, NROWS / 64), dim3(256), 0, stream>>>(
        stbf, WhT, bh, ep, key, out_mg, out_exp, out_nep);
}